// Round 11
// baseline (69.446 us; speedup 1.0000x reference)
//
#include <hip/hip_runtime.h>

#define D      64
#define K      512
#define Q_OFF  0            // out[0 .. 8388607]   quantized_ste (NCHW)
#define L_OFF  8388608      // out[8388608]        commitment loss
#define I_OFF  8388609      // out[8388609 .. ]    indices (131072)

// ws layout (floats)
#define WS_ET    0          // 512*64 transposed embeddings (fp32, exact)
#define WS_EN    32768      // 512 ||e||^2
#define WS_ENH   33280      // 512 0.5*||e||^2
#define WS_PART  33792      // partial loss sums (1024)

// B-fragment tables staged in out[] (quantized region, rewritten later)
#define B_LO_OFF 4096

// packed fixed-point selection constants
#define SEL_SCALE 16384.0f              // 2^14: resolution 6.1e-5
#define SEL_BIAS  (160.0f * 16384.0f)   // acc in (-160, 256) -> positive

typedef __attribute__((ext_vector_type(8))) short short8;   // 8 bf16 = 4 VGPRs
typedef __attribute__((ext_vector_type(4))) float f32x4;

static __device__ __forceinline__ unsigned short f2bf(float f) {
    unsigned u = __float_as_uint(f);
    u += 0x7fffu + ((u >> 16) & 1u);       // RTN-even
    return (unsigned short)(u >> 16);
}
static __device__ __forceinline__ float bf2f(unsigned short h) {
    return __uint_as_float(((unsigned)h) << 16);
}

// async global->LDS, 16 B per lane, linear layout (lds dest: wave base + lane*16)
__device__ __forceinline__ void gload_lds16(const float* g, float* l) {
    __builtin_amdgcn_global_load_lds(
        (const __attribute__((address_space(1))) unsigned int*)g,
        (__attribute__((address_space(3))) unsigned int*)l, 16, 0, 0);
}

// ---------------------------------------------------------------- prep ----
__global__ __launch_bounds__(256) void vq_prep(const float* __restrict__ E,
                                               float* __restrict__ ws,
                                               float* __restrict__ out) {
    int g = blockIdx.x * 256 + threadIdx.x;   // 0..2047 = (t, lane)
    int t = g >> 6, lane = g & 63;
    int col = lane & 15, kg = lane >> 4;
    int code = t * 16 + col;
    short8* bhp = (short8*)out;               // 64 KB
    short8* blp = (short8*)out + B_LO_OFF;    // next 64 KB
#pragma unroll
    for (int s = 0; s < 2; ++s) {
        short8 h, l;
#pragma unroll
        for (int j = 0; j < 8; ++j) {
            int k = s * 32 + kg * 8 + j;
            float v = -E[k * K + code];
            unsigned short hb = f2bf(v);
            h[j] = (short)hb;
            l[j] = (short)f2bf(v - bf2f(hb));
        }
        bhp[(t * 2 + s) * 64 + lane] = h;
        blp[(t * 2 + s) * 64 + lane] = l;
    }
    if (g < K) {
        float nsq = 0.f;
#pragma unroll 8
        for (int d = 0; d < D; ++d) {
            float v = E[d * K + g];
            ws[WS_ET + g * D + d] = v;
            nsq = fmaf(v, v, nsq);
        }
        ws[WS_EN + g]  = nsq;
        ws[WS_ENH + g] = 0.5f * nsq;
    }
}

// ---------------------------------------------------------------- dist ----
// 2048 blocks x 2 waves; wave owns 32 pixels (2 M-tiles) x 512 codes.
// T3+T4 pipeline: 32 single-tile chunks, 3 LDS buffers, counted
// s_waitcnt vmcnt(2) (stage of c+1 stays in flight ACROSS the raw barrier,
// never drained to 0), stage(c+2) issued right after the barrier.
// Packed fixed-point top-2 selection (first-min-wins = np.argmin).
__global__ __launch_bounds__(128, 4) void vq_dist(const float* __restrict__ x,
                                                  const float* __restrict__ ws,
                                                  float* __restrict__ out) {
    __shared__ float sbuf[3][1024];           // 3 x 4 KB: hi [0,512), lo [512,1024)
    __shared__ float senh[512];               // 0.5*||e||^2 table

    const int tid = threadIdx.x, w = tid >> 6, lane = tid & 63;
    const int col = lane & 15, rowg = lane >> 4;
    const int pixw = blockIdx.x * 64 + w * 32;

    const float* bh  = (const float*)out;                  // hi table (512 f/tile)
    const float* bl  = (const float*)out + B_LO_OFF * 4;   // lo table

    // prologue: senh first, then chunks 0,1 (so vmcnt(2) covers senh+chunk0)
    {
#pragma unroll
        for (int q = 0; q < 1; ++q) gload_lds16(ws + WS_ENH + tid * 4, senh + tid * 4);
        gload_lds16(bh + tid * 4,       sbuf[0] + tid * 4);
        gload_lds16(bl + tid * 4,       sbuf[0] + 512 + tid * 4);
        gload_lds16(bh + 512 + tid * 4, sbuf[1] + tid * 4);
        gload_lds16(bl + 512 + tid * 4, sbuf[1] + 512 + tid * 4);
    }

    // ---- load x fragments and split to bf16 hi/lo: A[mt][s]
    short8 ah[2][2], al[2][2];
#pragma unroll
    for (int mt = 0; mt < 2; ++mt) {
        int pix = pixw + mt * 16 + col;
        const float* xp = x + ((size_t)(pix >> 12) << 18) + (pix & 4095);
#pragma unroll
        for (int s = 0; s < 2; ++s) {
            short8 h, l;
#pragma unroll
            for (int j = 0; j < 8; ++j) {
                float v = xp[(size_t)(s * 32 + rowg * 8 + j) << 12];
                unsigned short hb = f2bf(v);
                h[j] = (short)hb;
                l[j] = (short)f2bf(v - bf2f(hb));
            }
            ah[mt][s] = h; al[mt][s] = l;
        }
    }

    unsigned m1[2][4], m2[2][4];
#pragma unroll
    for (int mt = 0; mt < 2; ++mt)
#pragma unroll
        for (int r = 0; r < 4; ++r) { m1[mt][r] = 0xFFFFFFFFu; m2[mt][r] = 0xFFFFFFFFu; }

    int cbuf = 0;                              // c % 3
    for (int c = 0; c < 32; ++c) {
        // stage(c) landed (own portion): all but the 2 newest (stage c+1) done.
        asm volatile("s_waitcnt vmcnt(2)" ::: "memory");
        __builtin_amdgcn_s_barrier();          // + other waves' portions landed;
        __builtin_amdgcn_sched_barrier(0);     //   pin: no ds_read hoists above

        // issue stage(c+2) into buf (c+2)%3 (its readers of the old content
        // all finished before the barrier above)
        if (c + 2 < 32) {
            int sb2 = (cbuf >= 1) ? cbuf - 1 : 2;
            const float* sh = bh + (c + 2) * 512;
            const float* sl = bl + (c + 2) * 512;
            gload_lds16(sh + tid * 4, sbuf[sb2] + tid * 4);
            gload_lds16(sl + tid * 4, sbuf[sb2] + 512 + tid * 4);
        }

        const short8* sb = (const short8*)sbuf[cbuf];
        const float ev = senh[c * 16 + col];
        const unsigned codev = (unsigned)(c * 16 + col);

        short8 cbh0 = sb[lane];
        short8 cbh1 = sb[64 + lane];
        short8 cbl0 = sb[128 + lane];
        short8 cbl1 = sb[192 + lane];

        f32x4 acc0 = { ev, ev, ev, ev };
        f32x4 acc1 = { ev, ev, ev, ev };
        __builtin_amdgcn_s_setprio(1);
        acc0 = __builtin_amdgcn_mfma_f32_16x16x32_bf16(ah[0][0], cbh0, acc0, 0, 0, 0);
        acc1 = __builtin_amdgcn_mfma_f32_16x16x32_bf16(ah[1][0], cbh0, acc1, 0, 0, 0);
        acc0 = __builtin_amdgcn_mfma_f32_16x16x32_bf16(al[0][0], cbh0, acc0, 0, 0, 0);
        acc1 = __builtin_amdgcn_mfma_f32_16x16x32_bf16(al[1][0], cbh0, acc1, 0, 0, 0);
        acc0 = __builtin_amdgcn_mfma_f32_16x16x32_bf16(ah[0][0], cbl0, acc0, 0, 0, 0);
        acc1 = __builtin_amdgcn_mfma_f32_16x16x32_bf16(ah[1][0], cbl0, acc1, 0, 0, 0);
        acc0 = __builtin_amdgcn_mfma_f32_16x16x32_bf16(ah[0][1], cbh1, acc0, 0, 0, 0);
        acc1 = __builtin_amdgcn_mfma_f32_16x16x32_bf16(ah[1][1], cbh1, acc1, 0, 0, 0);
        acc0 = __builtin_amdgcn_mfma_f32_16x16x32_bf16(al[0][1], cbh1, acc0, 0, 0, 0);
        acc1 = __builtin_amdgcn_mfma_f32_16x16x32_bf16(al[1][1], cbh1, acc1, 0, 0, 0);
        acc0 = __builtin_amdgcn_mfma_f32_16x16x32_bf16(ah[0][1], cbl1, acc0, 0, 0, 0);
        acc1 = __builtin_amdgcn_mfma_f32_16x16x32_bf16(ah[1][1], cbl1, acc1, 0, 0, 0);
        __builtin_amdgcn_s_setprio(0);

        // packed top-2 update: 6 VALU per acc element
#pragma unroll
        for (int r = 0; r < 4; ++r) {
            unsigned p0 = (((unsigned)fmaf(acc0[r], SEL_SCALE, SEL_BIAS)) << 9) + codev;
            m2[0][r] = min(m2[0][r], max(m1[0][r], p0));
            m1[0][r] = min(m1[0][r], p0);
            unsigned p1 = (((unsigned)fmaf(acc1[r], SEL_SCALE, SEL_BIAS)) << 9) + codev;
            m2[1][r] = min(m2[1][r], max(m1[1][r], p1));
            m1[1][r] = min(m1[1][r], p1);
        }

        cbuf = (cbuf == 2) ? 0 : cbuf + 1;
    }

    // cross-lane top-2 merge over the 16 code-columns, write packed (c1|c2<<16)
    unsigned* outu = (unsigned*)out;
#pragma unroll
    for (int mt = 0; mt < 2; ++mt)
#pragma unroll
        for (int r = 0; r < 4; ++r) {
            unsigned v1 = m1[mt][r], v2 = m2[mt][r];
#pragma unroll
            for (int m = 1; m < 16; m <<= 1) {
                unsigned o1 = (unsigned)__shfl_xor((int)v1, m, 16);
                unsigned o2 = (unsigned)__shfl_xor((int)v2, m, 16);
                v2 = min(max(v1, o1), min(v2, o2));
                v1 = min(v1, o1);
            }
            if (col == r) {
                int p = pixw + mt * 16 + rowg * 4 + r;
                unsigned c1 = v1 & 511u, c2 = v2 & 511u;
                outu[I_OFF + p] = c1 | (c2 << 16);
            }
        }
}

// ----------------------------------------------------------------- out ----
// 2 threads per pixel (d-halves). Exact fp32 recheck of the two candidates;
// half-dots combined via LDS in fixed (low+high) order so both threads of a
// pair pick the same winner.
__device__ __forceinline__ float dot32(const float* __restrict__ er,
                                       const float* __restrict__ xv) {
    const float4* e4 = (const float4*)er;
    float a0 = 0.f, a1 = 0.f, a2 = 0.f, a3 = 0.f;
#pragma unroll
    for (int q = 0; q < 8; ++q) {
        float4 e = e4[q];
        a0 = fmaf(xv[4*q+0], e.x, a0);
        a1 = fmaf(xv[4*q+1], e.y, a1);
        a2 = fmaf(xv[4*q+2], e.z, a2);
        a3 = fmaf(xv[4*q+3], e.w, a3);
    }
    return (a0 + a1) + (a2 + a3);
}

__global__ __launch_bounds__(256) void vq_out(const float* __restrict__ x,
                                              const float* __restrict__ ws,
                                              float* __restrict__ out,
                                              float* __restrict__ partial) {
    const float* ET = ws + WS_ET;
    const float* EN = ws + WS_EN;
    const int tid  = threadIdx.x;
    const int pl   = tid & 127;               // pixel-in-block
    const int half = tid >> 7;                // 0: d 0-31, 1: d 32-63
    const int n    = blockIdx.x * 128 + pl;
    const int b    = n >> 12;
    const int hw   = n & 4095;

    const float* xp = x + ((size_t)b << 18) + ((size_t)half << 17) + hw;  // + half*32*4096
    float xv[32];
#pragma unroll
    for (int d = 0; d < 32; ++d) xv[d] = xp[(size_t)d << 12];

    unsigned packed = ((const unsigned*)out)[I_OFF + n];
    int c1 = (int)(packed & 0xffffu), c2 = (int)(packed >> 16);

    float dp1 = dot32(ET + (c1 << 6) + half * 32, xv);
    float dp2 = dot32(ET + (c2 << 6) + half * 32, xv);

    __shared__ float2 sdot[2][128];
    sdot[half][pl] = make_float2(dp1, dp2);
    __syncthreads();
    float2 lo = sdot[0][pl], hi = sdot[1][pl];
    float d1 = fmaf(-2.f, lo.x + hi.x, EN[c1]);
    float d2 = fmaf(-2.f, lo.y + hi.y, EN[c2]);
    bool sw = (d2 < d1) || (d2 == d1 && c2 < c1);   // np.argmin: first min wins
    int bestk = sw ? c2 : c1;

    if (!half) out[I_OFF + n] = (float)bestk;

    const float* qv = ET + (bestk << 6) + half * 32;
    float* op = out + Q_OFF + ((size_t)b << 18) + ((size_t)half << 17) + hw;
    float lsum = 0.f;
#pragma unroll
    for (int d = 0; d < 32; ++d) {
        float qd = qv[d];
        op[(size_t)d << 12] = qd;
        float diff = xv[d] - qd;
        lsum = fmaf(diff, diff, lsum);
    }

    // deterministic block reduction of the loss
#pragma unroll
    for (int off = 32; off > 0; off >>= 1)
        lsum += __shfl_down(lsum, off, 64);
    __shared__ float wsum[4];
    if ((tid & 63) == 0) wsum[tid >> 6] = lsum;
    __syncthreads();
    if (tid == 0)
        partial[blockIdx.x] = (wsum[0] + wsum[1]) + (wsum[2] + wsum[3]);
}

__global__ __launch_bounds__(256) void vq_final(const float* __restrict__ partial,
                                                float* __restrict__ out) {
    int t = threadIdx.x;
    float s = ((partial[t] + partial[t + 256]) + partial[t + 512]) + partial[t + 768];
#pragma unroll
    for (int off = 32; off > 0; off >>= 1)
        s += __shfl_down(s, off, 64);
    __shared__ float wsum[4];
    if ((t & 63) == 0) wsum[t >> 6] = s;
    __syncthreads();
    if (t == 0)
        out[L_OFF] = ((wsum[0] + wsum[1]) + (wsum[2] + wsum[3])) * (1.f / 8388608.f);
}

extern "C" void kernel_launch(void* const* d_in, const int* in_sizes, int n_in,
                              void* d_out, int out_size, void* d_ws, size_t ws_size,
                              hipStream_t stream) {
    const float* x = (const float*)d_in[0];
    const float* E = (const float*)d_in[1];
    float* out = (float*)d_out;
    float* ws  = (float*)d_ws;

    hipLaunchKernelGGL(vq_prep,  dim3(8),    dim3(256), 0, stream, E, ws, out);
    hipLaunchKernelGGL(vq_dist,  dim3(2048), dim3(128), 0, stream, x, ws, out);
    hipLaunchKernelGGL(vq_out,   dim3(1024), dim3(256), 0, stream, x, ws, out, ws + WS_PART);
    hipLaunchKernelGGL(vq_final, dim3(1),    dim3(256), 0, stream, ws + WS_PART, out);
}

// Round 12
// 62.154 us; speedup vs baseline: 1.1173x; 1.1173x over previous
//
#include <hip/hip_runtime.h>

#define D      64
#define K      512
#define Q_OFF  0            // out[0 .. 8388607]   quantized_ste (NCHW)
#define L_OFF  8388608      // out[8388608]        commitment loss
#define I_OFF  8388609      // out[8388609 .. ]    indices (131072)

// ws layout (floats)
#define WS_ET    0          // 512*64 transposed embeddings (fp32, exact)
#define WS_EN    32768      // 512 ||e||^2
#define WS_ENH   33280      // 512 0.5*||e||^2
#define WS_PART  33792      // 2048 partial loss sums -> [33792, 35840)
#define WS_BH    36864      // hi B-fragment table, 16384 floats (64 KB)
#define WS_BL    53248      // lo B-fragment table, 16384 floats (64 KB)

// packed fixed-point selection constants
#define SEL_SCALE 16384.0f              // 2^14: resolution 6.1e-5
#define SEL_BIAS  (160.0f * 16384.0f)   // acc in (-160, 256) -> positive

typedef __attribute__((ext_vector_type(8))) short short8;   // 8 bf16 = 4 VGPRs
typedef __attribute__((ext_vector_type(4))) float f32x4;

static __device__ __forceinline__ unsigned short f2bf(float f) {
    unsigned u = __float_as_uint(f);
    u += 0x7fffu + ((u >> 16) & 1u);       // RTN-even
    return (unsigned short)(u >> 16);
}
static __device__ __forceinline__ float bf2f(unsigned short h) {
    return __uint_as_float(((unsigned)h) << 16);
}

// async global->LDS, 16 B per lane, linear layout (lds dest: wave base + lane*16)
__device__ __forceinline__ void gload_lds16(const float* g, float* l) {
    __builtin_amdgcn_global_load_lds(
        (const __attribute__((address_space(1))) unsigned int*)g,
        (__attribute__((address_space(3))) unsigned int*)l, 16, 0, 0);
}

// ---------------------------------------------------------------- prep ----
// B-fragment tables (hi/lo bf16 of -e) now live in ws (out's q region gets
// overwritten by the fused kernel). Also ET (fp32 transpose) + norms.
__global__ __launch_bounds__(256) void vq_prep(const float* __restrict__ E,
                                               float* __restrict__ ws) {
    int g = blockIdx.x * 256 + threadIdx.x;   // 0..2047 = (t, lane)
    int t = g >> 6, lane = g & 63;
    int col = lane & 15, kg = lane >> 4;
    int code = t * 16 + col;
    short8* bhp = (short8*)(ws + WS_BH);
    short8* blp = (short8*)(ws + WS_BL);
#pragma unroll
    for (int s = 0; s < 2; ++s) {
        short8 h, l;
#pragma unroll
        for (int j = 0; j < 8; ++j) {
            int k = s * 32 + kg * 8 + j;
            float v = -E[k * K + code];
            unsigned short hb = f2bf(v);
            h[j] = (short)hb;
            l[j] = (short)f2bf(v - bf2f(hb));
        }
        bhp[(t * 2 + s) * 64 + lane] = h;
        blp[(t * 2 + s) * 64 + lane] = l;
    }
    if (g < K) {
        float nsq = 0.f;
#pragma unroll 8
        for (int d = 0; d < D; ++d) {
            float v = E[d * K + g];
            ws[WS_ET + g * D + d] = v;
            nsq = fmaf(v, v, nsq);
        }
        ws[WS_EN + g]  = nsq;
        ws[WS_ENH + g] = 0.5f * nsq;
    }
}

// --------------------------------------------------------------- fused ----
// 2048 blocks x 2 waves; wave owns 32 pixels x 512 codes (r11 main loop:
// 3-buffer counted-vmcnt staging, packed fixed-point top-2). Epilogue fused:
// candidates parked in LDS, then 2 threads/pixel do the exact fp32 recheck
// (x re-read = L3 hit), NCHW gather-write, loss partial. vq_out deleted.
__device__ __forceinline__ float dot32(const float* __restrict__ er,
                                       const float* __restrict__ xv) {
    const float4* e4 = (const float4*)er;
    float a0 = 0.f, a1 = 0.f, a2 = 0.f, a3 = 0.f;
#pragma unroll
    for (int q = 0; q < 8; ++q) {
        float4 e = e4[q];
        a0 = fmaf(xv[4*q+0], e.x, a0);
        a1 = fmaf(xv[4*q+1], e.y, a1);
        a2 = fmaf(xv[4*q+2], e.z, a2);
        a3 = fmaf(xv[4*q+3], e.w, a3);
    }
    return (a0 + a1) + (a2 + a3);
}

__global__ __launch_bounds__(128, 4) void vq_fused(const float* __restrict__ x,
                                                   float* __restrict__ ws,
                                                   float* __restrict__ out,
                                                   float* __restrict__ partial) {
    __shared__ float sbuf[3][1024];           // 3 x 4 KB: hi [0,512), lo [512,1024)
    __shared__ float senh[512];               // 0.5*||e||^2 table
    __shared__ unsigned sc[64];               // candidate pairs per pixel
    __shared__ float2 sdot[2][64];            // half-dot exchange

    const int tid = threadIdx.x, w = tid >> 6, lane = tid & 63;
    const int col = lane & 15, rowg = lane >> 4;
    const int pixw = blockIdx.x * 64 + w * 32;

    const float* bh = ws + WS_BH;             // hi table (512 f/tile)
    const float* bl = ws + WS_BL;             // lo table

    // prologue: senh + chunks 0,1 (vmcnt(2) at c=0 covers senh+chunk0)
    gload_lds16(ws + WS_ENH + tid * 4, senh + tid * 4);
    gload_lds16(bh + tid * 4,       sbuf[0] + tid * 4);
    gload_lds16(bl + tid * 4,       sbuf[0] + 512 + tid * 4);
    gload_lds16(bh + 512 + tid * 4, sbuf[1] + tid * 4);
    gload_lds16(bl + 512 + tid * 4, sbuf[1] + 512 + tid * 4);

    // ---- load x fragments and split to bf16 hi/lo: A[mt][s]
    short8 ah[2][2], al[2][2];
#pragma unroll
    for (int mt = 0; mt < 2; ++mt) {
        int pix = pixw + mt * 16 + col;
        const float* xp = x + ((size_t)(pix >> 12) << 18) + (pix & 4095);
#pragma unroll
        for (int s = 0; s < 2; ++s) {
            short8 h, l;
#pragma unroll
            for (int j = 0; j < 8; ++j) {
                float v = xp[(size_t)(s * 32 + rowg * 8 + j) << 12];
                unsigned short hb = f2bf(v);
                h[j] = (short)hb;
                l[j] = (short)f2bf(v - bf2f(hb));
            }
            ah[mt][s] = h; al[mt][s] = l;
        }
    }

    unsigned m1[2][4], m2[2][4];
#pragma unroll
    for (int mt = 0; mt < 2; ++mt)
#pragma unroll
        for (int r = 0; r < 4; ++r) { m1[mt][r] = 0xFFFFFFFFu; m2[mt][r] = 0xFFFFFFFFu; }

    int cbuf = 0;                              // c % 3
    for (int c = 0; c < 32; ++c) {
        // stage(c) landed; stage(c+1) stays in flight (never drain mid-loop).
        // Last iteration: full drain (stage(31) has only itself outstanding).
        if (c < 31) asm volatile("s_waitcnt vmcnt(2)" ::: "memory");
        else        asm volatile("s_waitcnt vmcnt(0)" ::: "memory");
        __builtin_amdgcn_s_barrier();
        __builtin_amdgcn_sched_barrier(0);

        if (c + 2 < 32) {
            int sb2 = (cbuf >= 1) ? cbuf - 1 : 2;
            const float* sh = bh + (c + 2) * 512;
            const float* sl = bl + (c + 2) * 512;
            gload_lds16(sh + tid * 4, sbuf[sb2] + tid * 4);
            gload_lds16(sl + tid * 4, sbuf[sb2] + 512 + tid * 4);
        }

        const short8* sb = (const short8*)sbuf[cbuf];
        const float ev = senh[c * 16 + col];
        const unsigned codev = (unsigned)(c * 16 + col);

        short8 cbh0 = sb[lane];
        short8 cbh1 = sb[64 + lane];
        short8 cbl0 = sb[128 + lane];
        short8 cbl1 = sb[192 + lane];

        f32x4 acc0 = { ev, ev, ev, ev };
        f32x4 acc1 = { ev, ev, ev, ev };
        __builtin_amdgcn_s_setprio(1);
        acc0 = __builtin_amdgcn_mfma_f32_16x16x32_bf16(ah[0][0], cbh0, acc0, 0, 0, 0);
        acc1 = __builtin_amdgcn_mfma_f32_16x16x32_bf16(ah[1][0], cbh0, acc1, 0, 0, 0);
        acc0 = __builtin_amdgcn_mfma_f32_16x16x32_bf16(al[0][0], cbh0, acc0, 0, 0, 0);
        acc1 = __builtin_amdgcn_mfma_f32_16x16x32_bf16(al[1][0], cbh0, acc1, 0, 0, 0);
        acc0 = __builtin_amdgcn_mfma_f32_16x16x32_bf16(ah[0][0], cbl0, acc0, 0, 0, 0);
        acc1 = __builtin_amdgcn_mfma_f32_16x16x32_bf16(ah[1][0], cbl0, acc1, 0, 0, 0);
        acc0 = __builtin_amdgcn_mfma_f32_16x16x32_bf16(ah[0][1], cbh1, acc0, 0, 0, 0);
        acc1 = __builtin_amdgcn_mfma_f32_16x16x32_bf16(ah[1][1], cbh1, acc1, 0, 0, 0);
        acc0 = __builtin_amdgcn_mfma_f32_16x16x32_bf16(al[0][1], cbh1, acc0, 0, 0, 0);
        acc1 = __builtin_amdgcn_mfma_f32_16x16x32_bf16(al[1][1], cbh1, acc1, 0, 0, 0);
        acc0 = __builtin_amdgcn_mfma_f32_16x16x32_bf16(ah[0][1], cbl1, acc0, 0, 0, 0);
        acc1 = __builtin_amdgcn_mfma_f32_16x16x32_bf16(ah[1][1], cbl1, acc1, 0, 0, 0);
        __builtin_amdgcn_s_setprio(0);

        // packed top-2 update: 6 VALU per acc element
#pragma unroll
        for (int r = 0; r < 4; ++r) {
            unsigned p0 = (((unsigned)fmaf(acc0[r], SEL_SCALE, SEL_BIAS)) << 9) + codev;
            m2[0][r] = min(m2[0][r], max(m1[0][r], p0));
            m1[0][r] = min(m1[0][r], p0);
            unsigned p1 = (((unsigned)fmaf(acc1[r], SEL_SCALE, SEL_BIAS)) << 9) + codev;
            m2[1][r] = min(m2[1][r], max(m1[1][r], p1));
            m1[1][r] = min(m1[1][r], p1);
        }

        cbuf = (cbuf == 2) ? 0 : cbuf + 1;
    }

    // cross-lane top-2 merge; park candidate pair in LDS
#pragma unroll
    for (int mt = 0; mt < 2; ++mt)
#pragma unroll
        for (int r = 0; r < 4; ++r) {
            unsigned v1 = m1[mt][r], v2 = m2[mt][r];
#pragma unroll
            for (int m = 1; m < 16; m <<= 1) {
                unsigned o1 = (unsigned)__shfl_xor((int)v1, m, 16);
                unsigned o2 = (unsigned)__shfl_xor((int)v2, m, 16);
                v2 = min(max(v1, o1), min(v2, o2));
                v1 = min(v1, o1);
            }
            if (col == r)
                sc[w * 32 + mt * 16 + rowg * 4 + r] = (v1 & 511u) | ((v2 & 511u) << 16);
        }
    __syncthreads();

    // ---------------- fused epilogue: 2 threads per pixel (d-halves) ------
    const float* ET = ws + WS_ET;
    const float* EN = ws + WS_EN;
    const int pl   = tid & 63;                // pixel-in-block
    const int half = tid >> 6;                // 0: d 0-31, 1: d 32-63
    const int n    = blockIdx.x * 64 + pl;    // global pixel
    const int b    = n >> 12;
    const int hw   = n & 4095;

    unsigned pk = sc[pl];
    int c1 = (int)(pk & 0xffffu), c2 = (int)(pk >> 16);

    const float* xp2 = x + ((size_t)b << 18) + ((size_t)half << 17) + hw;
    float xv2[32];
#pragma unroll
    for (int d = 0; d < 32; ++d) xv2[d] = xp2[(size_t)d << 12];   // L3-resident

    float dp1 = dot32(ET + (c1 << 6) + half * 32, xv2);
    float dp2 = dot32(ET + (c2 << 6) + half * 32, xv2);
    sdot[half][pl] = make_float2(dp1, dp2);
    __syncthreads();
    float2 lo = sdot[0][pl], hi = sdot[1][pl];
    float d1 = fmaf(-2.f, lo.x + hi.x, EN[c1]);
    float d2 = fmaf(-2.f, lo.y + hi.y, EN[c2]);
    bool sw = (d2 < d1) || (d2 == d1 && c2 < c1);   // np.argmin: first min wins
    int bestk = sw ? c2 : c1;

    if (!half) out[I_OFF + n] = (float)bestk;

    const float* qv = ET + (bestk << 6) + half * 32;
    float* op = out + Q_OFF + ((size_t)b << 18) + ((size_t)half << 17) + hw;
    float lsum = 0.f;
#pragma unroll
    for (int d = 0; d < 32; ++d) {
        float qd = qv[d];
        op[(size_t)d << 12] = qd;
        float diff = xv2[d] - qd;
        lsum = fmaf(diff, diff, lsum);
    }

    // deterministic block reduction of the loss (2 waves)
#pragma unroll
    for (int off = 32; off > 0; off >>= 1)
        lsum += __shfl_down(lsum, off, 64);
    __shared__ float wsum[2];
    if ((tid & 63) == 0) wsum[tid >> 6] = lsum;
    __syncthreads();
    if (tid == 0)
        partial[blockIdx.x] = wsum[0] + wsum[1];
}

// --------------------------------------------------------------- final ----
__global__ __launch_bounds__(256) void vq_final(const float* __restrict__ partial,
                                                float* __restrict__ out) {
    int t = threadIdx.x;
    float s = 0.f;
#pragma unroll
    for (int i = 0; i < 8; ++i) s += partial[t + 256 * i];   // 2048 partials
#pragma unroll
    for (int off = 32; off > 0; off >>= 1)
        s += __shfl_down(s, off, 64);
    __shared__ float wsum[4];
    if ((t & 63) == 0) wsum[t >> 6] = s;
    __syncthreads();
    if (t == 0)
        out[L_OFF] = ((wsum[0] + wsum[1]) + (wsum[2] + wsum[3])) * (1.f / 8388608.f);
}

extern "C" void kernel_launch(void* const* d_in, const int* in_sizes, int n_in,
                              void* d_out, int out_size, void* d_ws, size_t ws_size,
                              hipStream_t stream) {
    const float* x = (const float*)d_in[0];
    const float* E = (const float*)d_in[1];
    float* out = (float*)d_out;
    float* ws  = (float*)d_ws;

    hipLaunchKernelGGL(vq_prep,  dim3(8),    dim3(256), 0, stream, E, ws);
    hipLaunchKernelGGL(vq_fused, dim3(2048), dim3(128), 0, stream, x, ws, out, ws + WS_PART);
    hipLaunchKernelGGL(vq_final, dim3(1),    dim3(256), 0, stream, ws + WS_PART, out);
}

// Round 13
// 61.349 us; speedup vs baseline: 1.1320x; 1.0131x over previous
//
#include <hip/hip_runtime.h>

#define D      64
#define K      512
#define Q_OFF  0            // out[0 .. 8388607]   quantized_ste (NCHW)
#define L_OFF  8388608      // out[8388608]        commitment loss
#define I_OFF  8388609      // out[8388609 .. ]    indices (131072)

// ws layout (floats)
#define WS_ET    0          // 512*64 transposed embeddings (fp32, exact)
#define WS_EN    32768      // 512 ||e||^2
#define WS_ENH   33280      // 512 0.5*||e||^2
#define WS_PART  33792      // 4096 partial loss sums -> [33792, 37888)
#define WS_BH    40960      // hi B-fragment table, 16384 floats (64 KB)
#define WS_BL    57344      // lo B-fragment table, 16384 floats (64 KB)

// packed fixed-point selection constants
#define SEL_SCALE 16384.0f              // 2^14: resolution 6.1e-5
#define SEL_BIAS  (160.0f * 16384.0f)   // acc in (-160, 256) -> positive

typedef __attribute__((ext_vector_type(8))) short short8;   // 8 bf16 = 4 VGPRs
typedef __attribute__((ext_vector_type(4))) float f32x4;

static __device__ __forceinline__ unsigned short f2bf(float f) {
    unsigned u = __float_as_uint(f);
    u += 0x7fffu + ((u >> 16) & 1u);       // RTN-even
    return (unsigned short)(u >> 16);
}
static __device__ __forceinline__ float bf2f(unsigned short h) {
    return __uint_as_float(((unsigned)h) << 16);
}

// async global->LDS, 16 B per lane, linear layout (lds dest: wave base + lane*16)
__device__ __forceinline__ void gload_lds16(const float* g, float* l) {
    __builtin_amdgcn_global_load_lds(
        (const __attribute__((address_space(1))) unsigned int*)g,
        (__attribute__((address_space(3))) unsigned int*)l, 16, 0, 0);
}

// ---------------------------------------------------------------- prep ----
__global__ __launch_bounds__(256) void vq_prep(const float* __restrict__ E,
                                               float* __restrict__ ws) {
    int g = blockIdx.x * 256 + threadIdx.x;   // 0..2047 = (t, lane)
    int t = g >> 6, lane = g & 63;
    int col = lane & 15, kg = lane >> 4;
    int code = t * 16 + col;
    short8* bhp = (short8*)(ws + WS_BH);
    short8* blp = (short8*)(ws + WS_BL);
#pragma unroll
    for (int s = 0; s < 2; ++s) {
        short8 h, l;
#pragma unroll
        for (int j = 0; j < 8; ++j) {
            int k = s * 32 + kg * 8 + j;
            float v = -E[k * K + code];
            unsigned short hb = f2bf(v);
            h[j] = (short)hb;
            l[j] = (short)f2bf(v - bf2f(hb));
        }
        bhp[(t * 2 + s) * 64 + lane] = h;
        blp[(t * 2 + s) * 64 + lane] = l;
    }
    if (g < K) {
        float nsq = 0.f;
#pragma unroll 8
        for (int d = 0; d < D; ++d) {
            float v = E[d * K + g];
            ws[WS_ET + g * D + d] = v;
            nsq = fmaf(v, v, nsq);
        }
        ws[WS_EN + g]  = nsq;
        ws[WS_ENH + g] = 0.5f * nsq;
    }
}

// --------------------------------------------------------------- fused ----
// TLP round: 4096 blocks x 2 waves, wave owns 16 pixels (1 M-tile) x 512
// codes. Small LDS (9.3 KB) + VGPR<=64 -> 16 blocks/CU = 8 waves/SIMD.
// Single-tile chunks (4 KB), double-buffered gload_lds staging.
// Packed fixed-point top-2; fused exact-recheck epilogue (4 threads/pixel).
__device__ __forceinline__ float dot16(const float* __restrict__ er,
                                       const float* __restrict__ xv) {
    const float4* e4 = (const float4*)er;
    float a0 = 0.f, a1 = 0.f, a2 = 0.f, a3 = 0.f;
#pragma unroll
    for (int q = 0; q < 4; ++q) {
        float4 e = e4[q];
        a0 = fmaf(xv[4*q+0], e.x, a0);
        a1 = fmaf(xv[4*q+1], e.y, a1);
        a2 = fmaf(xv[4*q+2], e.z, a2);
        a3 = fmaf(xv[4*q+3], e.w, a3);
    }
    return (a0 + a1) + (a2 + a3);
}

__global__ __launch_bounds__(128, 8) void vq_fused(const float* __restrict__ x,
                                                   float* __restrict__ ws,
                                                   float* __restrict__ out,
                                                   float* __restrict__ partial) {
    __shared__ float sbuf[2][1024];           // 2 x 4 KB: hi [0,512), lo [512,1024)
    __shared__ unsigned sc[32];               // candidate pairs per pixel
    __shared__ float2 sdot[4][32];            // quarter-dot exchange
    __shared__ float wsum[2];

    const int tid = threadIdx.x, w = tid >> 6, lane = tid & 63;
    const int col = lane & 15, rowg = lane >> 4;
    const int pixw = blockIdx.x * 32 + w * 16;

    const float* bh    = ws + WS_BH;          // hi table (512 f/tile)
    const float* bl    = ws + WS_BL;          // lo table
    const float* enh_g = ws + WS_ENH;

    // stage chunk 0 into buffer 0
    gload_lds16(bh + tid * 4, sbuf[0] + tid * 4);
    gload_lds16(bl + tid * 4, sbuf[0] + 512 + tid * 4);

    // ---- load x fragment and split to bf16 hi/lo: A[s]
    short8 ah[2], al[2];
    {
        int pix = pixw + col;
        const float* xp = x + ((size_t)(pix >> 12) << 18) + (pix & 4095);
#pragma unroll
        for (int s = 0; s < 2; ++s) {
            short8 h, l;
#pragma unroll
            for (int j = 0; j < 8; ++j) {
                float v = xp[(size_t)(s * 32 + rowg * 8 + j) << 12];
                unsigned short hb = f2bf(v);
                h[j] = (short)hb;
                l[j] = (short)f2bf(v - bf2f(hb));
            }
            ah[s] = h; al[s] = l;
        }
    }

    unsigned m1[4], m2[4];
#pragma unroll
    for (int r = 0; r < 4; ++r) { m1[r] = 0xFFFFFFFFu; m2[r] = 0xFFFFFFFFu; }

    __syncthreads();                           // chunk 0 staged

    for (int c = 0; c < 32; ++c) {
        // prefetch chunk c+1 into the other buffer
        if (c + 1 < 32) {
            const float* sh = bh + (c + 1) * 512;
            const float* sl = bl + (c + 1) * 512;
            float* db = sbuf[(c + 1) & 1];
            gload_lds16(sh + tid * 4, db + tid * 4);
            gload_lds16(sl + tid * 4, db + 512 + tid * 4);
        }

        const short8* sb = (const short8*)sbuf[c & 1];
        const float ev = enh_g[c * 16 + col];  // L1-hot 2KB table
        const unsigned codev = (unsigned)(c * 16 + col);

        short8 cbh0 = sb[lane];
        short8 cbh1 = sb[64 + lane];
        short8 cbl0 = sb[128 + lane];
        short8 cbl1 = sb[192 + lane];

        f32x4 acc = { ev, ev, ev, ev };
        __builtin_amdgcn_s_setprio(1);
        acc = __builtin_amdgcn_mfma_f32_16x16x32_bf16(ah[0], cbh0, acc, 0, 0, 0);
        acc = __builtin_amdgcn_mfma_f32_16x16x32_bf16(al[0], cbh0, acc, 0, 0, 0);
        acc = __builtin_amdgcn_mfma_f32_16x16x32_bf16(ah[0], cbl0, acc, 0, 0, 0);
        acc = __builtin_amdgcn_mfma_f32_16x16x32_bf16(ah[1], cbh1, acc, 0, 0, 0);
        acc = __builtin_amdgcn_mfma_f32_16x16x32_bf16(al[1], cbh1, acc, 0, 0, 0);
        acc = __builtin_amdgcn_mfma_f32_16x16x32_bf16(ah[1], cbl1, acc, 0, 0, 0);
        __builtin_amdgcn_s_setprio(0);

        // packed top-2 update: 6 VALU per acc element
#pragma unroll
        for (int r = 0; r < 4; ++r) {
            unsigned p0 = (((unsigned)fmaf(acc[r], SEL_SCALE, SEL_BIAS)) << 9) + codev;
            m2[r] = min(m2[r], max(m1[r], p0));
            m1[r] = min(m1[r], p0);
        }

        __syncthreads();   // stage c+1 landed; both waves done with buf (c&1)
    }

    // cross-lane top-2 merge over the 16 code-columns; park pairs in LDS
#pragma unroll
    for (int r = 0; r < 4; ++r) {
        unsigned v1 = m1[r], v2 = m2[r];
#pragma unroll
        for (int m = 1; m < 16; m <<= 1) {
            unsigned o1 = (unsigned)__shfl_xor((int)v1, m, 16);
            unsigned o2 = (unsigned)__shfl_xor((int)v2, m, 16);
            v2 = min(max(v1, o1), min(v2, o2));
            v1 = min(v1, o1);
        }
        if (col == r)
            sc[w * 16 + rowg * 4 + r] = (v1 & 511u) | ((v2 & 511u) << 16);
    }
    __syncthreads();

    // ---------------- fused epilogue: 4 threads per pixel (d-quarters) ----
    const float* ET = ws + WS_ET;
    const float* EN = ws + WS_EN;
    const int pl   = tid & 31;                // pixel-in-block
    const int part = tid >> 5;                // d-quarter 0..3
    const int n    = blockIdx.x * 32 + pl;    // global pixel
    const int b    = n >> 12;
    const int hw   = n & 4095;

    unsigned pk = sc[pl];
    int c1 = (int)(pk & 0xffffu), c2 = (int)(pk >> 16);

    const float* xp2 = x + ((size_t)b << 18) + ((size_t)part << 16) + hw;
    float xv2[16];
#pragma unroll
    for (int d = 0; d < 16; ++d) xv2[d] = xp2[(size_t)d << 12];   // cache-resident

    float dp1 = dot16(ET + (c1 << 6) + part * 16, xv2);
    float dp2 = dot16(ET + (c2 << 6) + part * 16, xv2);
    sdot[part][pl] = make_float2(dp1, dp2);
    __syncthreads();
    float2 q0 = sdot[0][pl], q1 = sdot[1][pl], q2 = sdot[2][pl], q3 = sdot[3][pl];
    float d1 = fmaf(-2.f, (q0.x + q1.x) + (q2.x + q3.x), EN[c1]);
    float d2 = fmaf(-2.f, (q0.y + q1.y) + (q2.y + q3.y), EN[c2]);
    bool sw = (d2 < d1) || (d2 == d1 && c2 < c1);   // np.argmin: first min wins
    int bestk = sw ? c2 : c1;

    if (part == 0) out[I_OFF + n] = (float)bestk;

    const float* qv = ET + (bestk << 6) + part * 16;
    float* op = out + Q_OFF + ((size_t)b << 18) + ((size_t)part << 16) + hw;
    float lsum = 0.f;
#pragma unroll
    for (int d = 0; d < 16; ++d) {
        float qd = qv[d];
        op[(size_t)d << 12] = qd;
        float diff = xv2[d] - qd;
        lsum = fmaf(diff, diff, lsum);
    }

    // deterministic block reduction of the loss (2 waves)
#pragma unroll
    for (int off = 32; off > 0; off >>= 1)
        lsum += __shfl_down(lsum, off, 64);
    if ((tid & 63) == 0) wsum[tid >> 6] = lsum;
    __syncthreads();
    if (tid == 0)
        partial[blockIdx.x] = wsum[0] + wsum[1];
}

// --------------------------------------------------------------- final ----
__global__ __launch_bounds__(256) void vq_final(const float* __restrict__ partial,
                                                float* __restrict__ out) {
    int t = threadIdx.x;
    float s = 0.f;
#pragma unroll
    for (int i = 0; i < 16; ++i) s += partial[t + 256 * i];   // 4096 partials
#pragma unroll
    for (int off = 32; off > 0; off >>= 1)
        s += __shfl_down(s, off, 64);
    __shared__ float wsum[4];
    if ((t & 63) == 0) wsum[t >> 6] = s;
    __syncthreads();
    if (t == 0)
        out[L_OFF] = ((wsum[0] + wsum[1]) + (wsum[2] + wsum[3])) * (1.f / 8388608.f);
}

extern "C" void kernel_launch(void* const* d_in, const int* in_sizes, int n_in,
                              void* d_out, int out_size, void* d_ws, size_t ws_size,
                              hipStream_t stream) {
    const float* x = (const float*)d_in[0];
    const float* E = (const float*)d_in[1];
    float* out = (float*)d_out;
    float* ws  = (float*)d_ws;

    hipLaunchKernelGGL(vq_prep,  dim3(8),    dim3(256), 0, stream, E, ws);
    hipLaunchKernelGGL(vq_fused, dim3(4096), dim3(128), 0, stream, x, ws, out, ws + WS_PART);
    hipLaunchKernelGGL(vq_final, dim3(1),    dim3(256), 0, stream, ws + WS_PART, out);
}